// Round 8
// baseline (392.394 us; speedup 1.0000x reference)
//
#include <hip/hip_runtime.h>
#include <hip/hip_bf16.h>

#define OUT_SCALE 0.030197383422318501f  // exp(-3.5)

typedef __attribute__((ext_vector_type(8))) short bf16x8;
typedef __attribute__((ext_vector_type(4))) float f32x4;

#define EL_BLOCKS 2048
#define NUC_BLOCKS 2048

__device__ __forceinline__ unsigned pk2(float a, float b) {
  __hip_bfloat162 h = __float22bfloat162_rn(make_float2(a, b));
  unsigned u;
  __builtin_memcpy(&u, &h, 4);
  return u;
}

__device__ __forceinline__ float silu_f(float h) {
  return h * __builtin_amdgcn_rcpf(1.0f + __expf(-h));
}

// ---------------------------------------------------------------------------
// Prep: pack w1_el / w1_nuc into MFMA fragment layout, bf16.
// Fragment (mlp, kk, kg, col) = 8 bf16 of w1[kk*32+kg*8 .. +8)[col].
// ---------------------------------------------------------------------------
__global__ void prep_w1(const float* __restrict__ w1a,
                        const float* __restrict__ w1b,
                        unsigned short* __restrict__ wp) {
  int gid = blockIdx.x * 256 + threadIdx.x;  // 16384 fragments
  const float* w1 = (gid < 8192) ? w1a : w1b;
  int rem = gid & 8191;
  int kk = rem >> 10;
  int kg = (rem >> 8) & 3;
  int col = rem & 255;
  const float* src = w1 + (kk * 32 + kg * 8) * 256 + col;
  uint4 v;
  v.x = pk2(src[0 * 256], src[1 * 256]);
  v.y = pk2(src[2 * 256], src[3 * 256]);
  v.z = pk2(src[4 * 256], src[5 * 256]);
  v.w = pk2(src[6 * 256], src[7 * 256]);
  *(uint4*)(wp + (size_t)gid * 8) = v;
}

// ---------------------------------------------------------------------------
// Fused main kernel, 512 threads = 8 waves x 32 hidden-cols, 8 pairs/block
// for BOTH paths. el: 256 padded rows = 8 chunks of 32 (chunk == pair).
// nuc: 64 rows = 2 chunks of 32.
// Phase 1: emb contribution (+b1) once per pair -> s_embc[8][256].
// Main: double-buffered 32-row msg chunks, issue-early/write-late, one
// barrier per chunk; per tile only 4 msg MFMAs + acc-init ds_read.
// LDS ~38KB, target 64 VGPR -> 4 blocks/CU, 32 waves/CU.
// ---------------------------------------------------------------------------
__global__ __launch_bounds__(512, 8) void bf_main_kernel(
    const float* __restrict__ rs, const float* __restrict__ msg_el,
    const float* __restrict__ msg_nuc, const float* __restrict__ emb,
    const unsigned short* __restrict__ wpk,
    const float* __restrict__ b1_el, const float* __restrict__ w2_el,
    const float* __restrict__ b2_el,
    const float* __restrict__ b1_nuc, const float* __restrict__ w2_nuc,
    const float* __restrict__ b2_nuc,
    const float* __restrict__ coords, const float* __restrict__ chg,
    float* __restrict__ out) {
  __shared__ __align__(16) unsigned short s_emb[16 * 128];   // 4 KB
  __shared__ __align__(16) unsigned short s_msg[2 * 32 * 128];  // 16 KB
  __shared__ __align__(16) float s_embc[8 * 256];            // 8 KB
  __shared__ __align__(16) float s_w2[256];                  // 1 KB
  __shared__ float s_fp[8][256];                             // 8 KB
  __shared__ float s_ps[8][4];
  __shared__ float s_decay[8];

  const int tid = threadIdx.x;
  const int bid = blockIdx.x;
  const int lane = tid & 63;
  const int wv = tid >> 6;
  const int cIdx = lane & 15, kg = lane >> 4;
  const int lr = tid >> 4, ch2 = tid & 15;  // staging row / chunk

  if (bid < EL_BLOCKS) {
    // ======================= EL PATH =======================
    const int gp0 = bid * 8;
    const float* msg = msg_el;

    if (tid < 32) ((float*)s_ps)[tid] = 0.0f;

    // ---- stage emb (8 pairs, swizzled; zero rows 8..15) ----
    {
      int p = tid >> 4, ch = tid & 15;
      if (tid < 128) {
        const float* src = emb + (gp0 + p) * 128 + ch * 8;
        float4 v0 = *(const float4*)src;
        float4 v1 = *(const float4*)(src + 4);
        uint4 pk;
        pk.x = pk2(v0.x, v0.y); pk.y = pk2(v0.z, v0.w);
        pk.z = pk2(v1.x, v1.y); pk.w = pk2(v1.z, v1.w);
        *(uint4*)(s_emb + p * 128 + (ch ^ p) * 8) = pk;
      } else if (tid < 256) {
        uint4 z = {0u, 0u, 0u, 0u};
        *(uint4*)(s_emb + p * 128 + (ch ^ (p & 15)) * 8) = z;
      }
      if (tid < 256) s_w2[tid] = w2_el[tid];
    }

    // ---- W1 emb-half fragments ----
    bf16x8 Bf[4][2];
    const int col = wv * 32 + cIdx;
#pragma unroll
    for (int nt = 0; nt < 2; ++nt)
#pragma unroll
      for (int kk = 0; kk < 4; ++kk)
        Bf[kk][nt] = *(const bf16x8*)(
            wpk + (size_t)((kk * 4 + kg) * 256 + col + nt * 16) * 8);

    // ---- issue chunk-0 loads (chunk == pair; j = lr, clamp 31->30) ----
    const int jc = (lr < 31) ? lr : 30;
    const float* mptr = msg + (size_t)(gp0 * 31 + jc) * 128 + ch2 * 8;
    float4 la = *(const float4*)mptr;
    float4 lb = *(const float4*)(mptr + 4);
    mptr += 31 * 128;

    __syncthreads();

    // ---- phase 1: emb contribution per pair, +b1 at store ----
    {
      f32x4 aE0 = {0, 0, 0, 0}, aE1 = {0, 0, 0, 0};
#pragma unroll
      for (int kk = 0; kk < 4; ++kk) {
        bf16x8 a = *(const bf16x8*)(
            s_emb + cIdx * 128 + ((kk * 4 + kg) ^ cIdx) * 8);
        aE0 = __builtin_amdgcn_mfma_f32_16x16x32_bf16(Bf[kk][0], a, aE0, 0, 0, 0);
        aE1 = __builtin_amdgcn_mfma_f32_16x16x32_bf16(Bf[kk][1], a, aE1, 0, 0, 0);
      }
      if (cIdx < 8) {
        f32x4 b1a = *(const f32x4*)(b1_el + wv * 32 + kg * 4);
        f32x4 b1b = *(const f32x4*)(b1_el + wv * 32 + 16 + kg * 4);
        *(f32x4*)(s_embc + cIdx * 256 + wv * 32 + kg * 4) = aE0 + b1a;
        *(f32x4*)(s_embc + cIdx * 256 + wv * 32 + 16 + kg * 4) = aE1 + b1b;
      }
    }

    // ---- reload Bf with msg-half fragments ----
#pragma unroll
    for (int nt = 0; nt < 2; ++nt)
#pragma unroll
      for (int kk = 0; kk < 4; ++kk)
        Bf[kk][nt] = *(const bf16x8*)(
            wpk + (size_t)(((kk + 4) * 4 + kg) * 256 + col + nt * 16) * 8);

    // ---- write chunk 0 ----
    {
      uint4 pk;
      pk.x = pk2(la.x, la.y); pk.y = pk2(la.z, la.w);
      pk.z = pk2(lb.x, lb.y); pk.w = pk2(lb.z, lb.w);
      *(uint4*)(s_msg + lr * 128 + ((ch2 ^ (lr & 15)) * 8)) = pk;
    }

    __syncthreads();

    // ---- main: 8 chunks x 2 tiles ----
#pragma unroll 1
    for (int c = 0; c < 8; ++c) {
      if (c < 7) {
        la = *(const float4*)mptr;
        lb = *(const float4*)(mptr + 4);
        mptr += 31 * 128;
      }
      const unsigned short* mb = s_msg + (c & 1) * 4096;
      const float* ec = s_embc + c * 256;
#pragma unroll
      for (int tt = 0; tt < 2; ++tt) {
        f32x4 acc0 = *(const f32x4*)(ec + wv * 32 + kg * 4);
        f32x4 acc1 = *(const f32x4*)(ec + wv * 32 + 16 + kg * 4);
        const unsigned short* mp = mb + (tt * 16 + cIdx) * 128;
#pragma unroll
        for (int kk = 0; kk < 4; ++kk) {
          bf16x8 a = *(const bf16x8*)(mp + ((kk * 4 + kg) ^ cIdx) * 8);
          acc0 = __builtin_amdgcn_mfma_f32_16x16x32_bf16(Bf[kk][0], a, acc0, 0, 0, 0);
          acc1 = __builtin_amdgcn_mfma_f32_16x16x32_bf16(Bf[kk][1], a, acc1, 0, 0, 0);
        }
        f32x4 w2a = *(const f32x4*)(s_w2 + wv * 32 + kg * 4);
        f32x4 w2b = *(const f32x4*)(s_w2 + wv * 32 + 16 + kg * 4);
        float p0 = 0.0f, p1 = 0.0f;
#pragma unroll
        for (int reg = 0; reg < 4; ++reg) {
          p0 += silu_f(acc0[reg]) * w2a[reg];
          p1 += silu_f(acc1[reg]) * w2b[reg];
        }
        float v = p0 + p1;
        v += __shfl_xor(v, 16);
        v += __shfl_xor(v, 32);
        if (kg == 0) s_fp[wv][(c * 2 + tt) * 16 + cIdx] = v;
      }
      if (c < 7) {
        uint4 pk;
        pk.x = pk2(la.x, la.y); pk.y = pk2(la.z, la.w);
        pk.z = pk2(lb.x, lb.y); pk.w = pk2(lb.z, lb.w);
        *(uint4*)(s_msg + ((c + 1) & 1) * 4096 + lr * 128 +
                  ((ch2 ^ (lr & 15)) * 8)) = pk;
      }
      __syncthreads();
    }

    // ---- geometry epilogue ----
    if (tid < 248) {
      int p = tid / 31, jj = tid - p * 31;
      int gp = gp0 + p, b = gp >> 5, i = gp & 31;
      int jidx = jj + (jj >= i ? 1 : 0);
      const float* rsb = rs + b * 96;
      float dx = rsb[jidx * 3 + 0] - rsb[i * 3 + 0];
      float dy = rsb[jidx * 3 + 1] - rsb[i * 3 + 1];
      float dz = rsb[jidx * 3 + 2] - rsb[i * 3 + 2];
      float tq = dx * dx + dy * dy + dz * dz;
      int row = p * 32 + jj;
      float f = b2_el[0];
#pragma unroll
      for (int w = 0; w < 8; ++w) f += s_fp[w][row];
      float g = f * __builtin_amdgcn_rcpf(1.0f + tq * sqrtf(tq));
      atomicAdd(&s_ps[p][0], g * dx);
      atomicAdd(&s_ps[p][1], g * dy);
      atomicAdd(&s_ps[p][2], g * dz);
    }
    if (tid < 8) {
      int gp = gp0 + tid, b = gp >> 5, i = gp & 31;
      float x = rs[(b * 32 + i) * 3 + 0];
      float y = rs[(b * 32 + i) * 3 + 1];
      float z = rs[(b * 32 + i) * 3 + 2];
      float dcy = 1.0f;
#pragma unroll
      for (int n = 0; n < 8; ++n) {
        float dx = x - coords[n * 3 + 0];
        float dy = y - coords[n * 3 + 1];
        float dz = z - coords[n * 3 + 2];
        float tq = dx * dx + dy * dy + dz * dz;
        float zc = chg[n];
        dcy *= tanhf(4.0f * tq * zc * zc);
      }
      s_decay[tid] = dcy;
    }
    __syncthreads();
    if (tid < 24) {
      int p = tid / 3, c = tid - p * 3;
      int gp = gp0 + p;
      atomicAdd(&out[gp * 3 + c], OUT_SCALE * s_decay[p] * s_ps[p][c]);
    }
  } else {
    // ======================= NUC PATH =======================
    const int nbid = bid - EL_BLOCKS;
    const int gp0 = nbid * 8;
    const float* msg = msg_nuc;
    const unsigned short* wp = wpk + 8192 * 8;

    if (tid < 32) ((float*)s_ps)[tid] = 0.0f;

    {
      int p = tid >> 4, ch = tid & 15;
      if (tid < 128) {
        const float* src = emb + (gp0 + p) * 128 + ch * 8;
        float4 v0 = *(const float4*)src;
        float4 v1 = *(const float4*)(src + 4);
        uint4 pk;
        pk.x = pk2(v0.x, v0.y); pk.y = pk2(v0.z, v0.w);
        pk.z = pk2(v1.x, v1.y); pk.w = pk2(v1.z, v1.w);
        *(uint4*)(s_emb + p * 128 + (ch ^ p) * 8) = pk;
      } else if (tid < 256) {
        uint4 z = {0u, 0u, 0u, 0u};
        *(uint4*)(s_emb + p * 128 + (ch ^ (p & 15)) * 8) = z;
      }
      if (tid < 256) s_w2[tid] = w2_nuc[tid];
    }

    bf16x8 Bf[4][2];
    const int col = wv * 32 + cIdx;
#pragma unroll
    for (int nt = 0; nt < 2; ++nt)
#pragma unroll
      for (int kk = 0; kk < 4; ++kk)
        Bf[kk][nt] = *(const bf16x8*)(
            wp + (size_t)((kk * 4 + kg) * 256 + col + nt * 16) * 8);

    const float* mptr = msg + (size_t)(gp0 * 8 + lr) * 128 + ch2 * 8;
    float4 la = *(const float4*)mptr;
    float4 lb = *(const float4*)(mptr + 4);
    mptr += 32 * 128;

    __syncthreads();

    {
      f32x4 aE0 = {0, 0, 0, 0}, aE1 = {0, 0, 0, 0};
#pragma unroll
      for (int kk = 0; kk < 4; ++kk) {
        bf16x8 a = *(const bf16x8*)(
            s_emb + cIdx * 128 + ((kk * 4 + kg) ^ cIdx) * 8);
        aE0 = __builtin_amdgcn_mfma_f32_16x16x32_bf16(Bf[kk][0], a, aE0, 0, 0, 0);
        aE1 = __builtin_amdgcn_mfma_f32_16x16x32_bf16(Bf[kk][1], a, aE1, 0, 0, 0);
      }
      if (cIdx < 8) {
        f32x4 b1a = *(const f32x4*)(b1_nuc + wv * 32 + kg * 4);
        f32x4 b1b = *(const f32x4*)(b1_nuc + wv * 32 + 16 + kg * 4);
        *(f32x4*)(s_embc + cIdx * 256 + wv * 32 + kg * 4) = aE0 + b1a;
        *(f32x4*)(s_embc + cIdx * 256 + wv * 32 + 16 + kg * 4) = aE1 + b1b;
      }
    }

#pragma unroll
    for (int nt = 0; nt < 2; ++nt)
#pragma unroll
      for (int kk = 0; kk < 4; ++kk)
        Bf[kk][nt] = *(const bf16x8*)(
            wp + (size_t)(((kk + 4) * 4 + kg) * 256 + col + nt * 16) * 8);

    {
      uint4 pk;
      pk.x = pk2(la.x, la.y); pk.y = pk2(la.z, la.w);
      pk.z = pk2(lb.x, lb.y); pk.w = pk2(lb.z, lb.w);
      *(uint4*)(s_msg + lr * 128 + ((ch2 ^ (lr & 15)) * 8)) = pk;
    }

    __syncthreads();

#pragma unroll 1
    for (int c = 0; c < 2; ++c) {
      if (c < 1) {
        la = *(const float4*)mptr;
        lb = *(const float4*)(mptr + 4);
      }
      const unsigned short* mb = s_msg + (c & 1) * 4096;
#pragma unroll
      for (int tt = 0; tt < 2; ++tt) {
        int p = 4 * c + 2 * tt + (cIdx >> 3);
        const float* ec = s_embc + p * 256;
        f32x4 acc0 = *(const f32x4*)(ec + wv * 32 + kg * 4);
        f32x4 acc1 = *(const f32x4*)(ec + wv * 32 + 16 + kg * 4);
        const unsigned short* mp = mb + (tt * 16 + cIdx) * 128;
#pragma unroll
        for (int kk = 0; kk < 4; ++kk) {
          bf16x8 a = *(const bf16x8*)(mp + ((kk * 4 + kg) ^ cIdx) * 8);
          acc0 = __builtin_amdgcn_mfma_f32_16x16x32_bf16(Bf[kk][0], a, acc0, 0, 0, 0);
          acc1 = __builtin_amdgcn_mfma_f32_16x16x32_bf16(Bf[kk][1], a, acc1, 0, 0, 0);
        }
        f32x4 w2a = *(const f32x4*)(s_w2 + wv * 32 + kg * 4);
        f32x4 w2b = *(const f32x4*)(s_w2 + wv * 32 + 16 + kg * 4);
        float p0 = 0.0f, p1 = 0.0f;
#pragma unroll
        for (int reg = 0; reg < 4; ++reg) {
          p0 += silu_f(acc0[reg]) * w2a[reg];
          p1 += silu_f(acc1[reg]) * w2b[reg];
        }
        float v = p0 + p1;
        v += __shfl_xor(v, 16);
        v += __shfl_xor(v, 32);
        if (kg == 0) s_fp[wv][(c * 2 + tt) * 16 + cIdx] = v;
      }
      if (c < 1) {
        uint4 pk;
        pk.x = pk2(la.x, la.y); pk.y = pk2(la.z, la.w);
        pk.z = pk2(lb.x, lb.y); pk.w = pk2(lb.z, lb.w);
        *(uint4*)(s_msg + 4096 + lr * 128 + ((ch2 ^ (lr & 15)) * 8)) = pk;
      }
      __syncthreads();
    }

    if (tid < 64) {
      int p = tid >> 3, n = tid & 7;
      int gp = gp0 + p, b = gp >> 5, i = gp & 31;
      float dx = rs[(b * 32 + i) * 3 + 0] - coords[n * 3 + 0];
      float dy = rs[(b * 32 + i) * 3 + 1] - coords[n * 3 + 1];
      float dz = rs[(b * 32 + i) * 3 + 2] - coords[n * 3 + 2];
      float tq = dx * dx + dy * dy + dz * dz;
      float f = b2_nuc[0];
#pragma unroll
      for (int w = 0; w < 8; ++w) f += s_fp[w][tid];
      float g = f * __builtin_amdgcn_rcpf(1.0f + tq * sqrtf(tq));
      atomicAdd(&s_ps[p][0], g * dx);
      atomicAdd(&s_ps[p][1], g * dy);
      atomicAdd(&s_ps[p][2], g * dz);
    }
    if (tid < 8) {
      int gp = gp0 + tid, b = gp >> 5, i = gp & 31;
      float x = rs[(b * 32 + i) * 3 + 0];
      float y = rs[(b * 32 + i) * 3 + 1];
      float z = rs[(b * 32 + i) * 3 + 2];
      float dcy = 1.0f;
#pragma unroll
      for (int n = 0; n < 8; ++n) {
        float dx = x - coords[n * 3 + 0];
        float dy = y - coords[n * 3 + 1];
        float dz = z - coords[n * 3 + 2];
        float tq = dx * dx + dy * dy + dz * dz;
        float zc = chg[n];
        dcy *= tanhf(4.0f * tq * zc * zc);
      }
      s_decay[tid] = dcy;
    }
    __syncthreads();
    if (tid < 24) {
      int p = tid / 3, c = tid - p * 3;
      int gp = gp0 + p;
      atomicAdd(&out[gp * 3 + c], OUT_SCALE * s_decay[p] * s_ps[p][c]);
    }
  }
}

extern "C" void kernel_launch(void* const* d_in, const int* in_sizes, int n_in,
                              void* d_out, int out_size, void* d_ws, size_t ws_size,
                              hipStream_t stream) {
  const float* rs       = (const float*)d_in[0];
  const float* coords   = (const float*)d_in[1];
  const float* msg_el   = (const float*)d_in[2];
  const float* msg_nuc  = (const float*)d_in[3];
  const float* emb      = (const float*)d_in[4];
  const float* w1_el    = (const float*)d_in[5];
  const float* b1_el    = (const float*)d_in[6];
  const float* w2_el    = (const float*)d_in[7];
  const float* b2_el    = (const float*)d_in[8];
  const float* w1_nuc   = (const float*)d_in[9];
  const float* b1_nuc   = (const float*)d_in[10];
  const float* w2_nuc   = (const float*)d_in[11];
  const float* b2_nuc   = (const float*)d_in[12];
  const float* chg      = (const float*)d_in[13];
  float* out = (float*)d_out;

  unsigned short* wpk = (unsigned short*)d_ws;  // 256 KB used

  hipMemsetAsync(out, 0, (size_t)out_size * sizeof(float), stream);
  prep_w1<<<64, 256, 0, stream>>>(w1_el, w1_nuc, wpk);
  bf_main_kernel<<<EL_BLOCKS + NUC_BLOCKS, 512, 0, stream>>>(
      rs, msg_el, msg_nuc, emb, wpk, b1_el, w2_el, b2_el, b1_nuc, w2_nuc,
      b2_nuc, coords, chg, out);
}

// Round 9
// 181.298 us; speedup vs baseline: 2.1644x; 2.1644x over previous
//
#include <hip/hip_runtime.h>
#include <hip/hip_bf16.h>

#define OUT_SCALE 0.030197383422318501f  // exp(-3.5)

typedef __attribute__((ext_vector_type(8))) short bf16x8;
typedef __attribute__((ext_vector_type(4))) float f32x4;

#define EL_BLOCKS 2048
#define NUC_BLOCKS 2048

__device__ __forceinline__ unsigned pk2(float a, float b) {
  __hip_bfloat162 h = __float22bfloat162_rn(make_float2(a, b));
  unsigned u;
  __builtin_memcpy(&u, &h, 4);
  return u;
}

__device__ __forceinline__ float silu_f(float h) {
  return h * __builtin_amdgcn_rcpf(1.0f + __expf(-h));
}

// ---------------------------------------------------------------------------
// Prep: pack w1_el / w1_nuc into MFMA fragment layout, bf16.
// Fragment (mlp, kk, kg, col) = 8 bf16 of w1[kk*32+kg*8 .. +8)[col].
// ---------------------------------------------------------------------------
__global__ void prep_w1(const float* __restrict__ w1a,
                        const float* __restrict__ w1b,
                        unsigned short* __restrict__ wp) {
  int gid = blockIdx.x * 256 + threadIdx.x;  // 16384 fragments
  const float* w1 = (gid < 8192) ? w1a : w1b;
  int rem = gid & 8191;
  int kk = rem >> 10;
  int kg = (rem >> 8) & 3;
  int col = rem & 255;
  const float* src = w1 + (kk * 32 + kg * 8) * 256 + col;
  uint4 v;
  v.x = pk2(src[0 * 256], src[1 * 256]);
  v.y = pk2(src[2 * 256], src[3 * 256]);
  v.z = pk2(src[4 * 256], src[5 * 256]);
  v.w = pk2(src[6 * 256], src[7 * 256]);
  *(uint4*)(wp + (size_t)gid * 8) = v;
}

// ---------------------------------------------------------------------------
// Fused main kernel, 512 threads = 8 waves x 32 hidden-cols, 8 pairs/block
// for BOTH paths. el: 256 padded rows = 8 chunks of 32 (chunk == pair).
// nuc: 64 rows = 2 chunks of 32.
// Phase 1: emb contribution (+b1) once per pair -> s_embc[8][256].
// Main: double-buffered 32-row msg chunks, issue-early/write-late, one
// barrier per chunk; per tile only 4 msg MFMAs + acc-init ds_read.
// LDS ~38KB; launch_bounds(512,6): ~85-reg budget, 60 live -> NO SPILL,
// 3 blocks/CU = 24 waves/CU (75%). (512,8) spilled catastrophically (r8).
// ---------------------------------------------------------------------------
__global__ __launch_bounds__(512, 6) void bf_main_kernel(
    const float* __restrict__ rs, const float* __restrict__ msg_el,
    const float* __restrict__ msg_nuc, const float* __restrict__ emb,
    const unsigned short* __restrict__ wpk,
    const float* __restrict__ b1_el, const float* __restrict__ w2_el,
    const float* __restrict__ b2_el,
    const float* __restrict__ b1_nuc, const float* __restrict__ w2_nuc,
    const float* __restrict__ b2_nuc,
    const float* __restrict__ coords, const float* __restrict__ chg,
    float* __restrict__ out) {
  __shared__ __align__(16) unsigned short s_emb[16 * 128];   // 4 KB
  __shared__ __align__(16) unsigned short s_msg[2 * 32 * 128];  // 16 KB
  __shared__ __align__(16) float s_embc[8 * 256];            // 8 KB
  __shared__ __align__(16) float s_w2[256];                  // 1 KB
  __shared__ float s_fp[8][256];                             // 8 KB
  __shared__ float s_ps[8][4];
  __shared__ float s_decay[8];

  const int tid = threadIdx.x;
  const int bid = blockIdx.x;
  const int lane = tid & 63;
  const int wv = tid >> 6;
  const int cIdx = lane & 15, kg = lane >> 4;
  const int lr = tid >> 4, ch2 = tid & 15;  // staging row / chunk

  if (bid < EL_BLOCKS) {
    // ======================= EL PATH =======================
    const int gp0 = bid * 8;
    const float* msg = msg_el;

    if (tid < 32) ((float*)s_ps)[tid] = 0.0f;

    // ---- stage emb (8 pairs, swizzled; zero rows 8..15) ----
    {
      int p = tid >> 4, ch = tid & 15;
      if (tid < 128) {
        const float* src = emb + (gp0 + p) * 128 + ch * 8;
        float4 v0 = *(const float4*)src;
        float4 v1 = *(const float4*)(src + 4);
        uint4 pk;
        pk.x = pk2(v0.x, v0.y); pk.y = pk2(v0.z, v0.w);
        pk.z = pk2(v1.x, v1.y); pk.w = pk2(v1.z, v1.w);
        *(uint4*)(s_emb + p * 128 + (ch ^ p) * 8) = pk;
      } else if (tid < 256) {
        uint4 z = {0u, 0u, 0u, 0u};
        *(uint4*)(s_emb + p * 128 + (ch ^ (p & 15)) * 8) = z;
      }
      if (tid < 256) s_w2[tid] = w2_el[tid];
    }

    // ---- W1 emb-half fragments ----
    bf16x8 Bf[4][2];
    const int col = wv * 32 + cIdx;
#pragma unroll
    for (int nt = 0; nt < 2; ++nt)
#pragma unroll
      for (int kk = 0; kk < 4; ++kk)
        Bf[kk][nt] = *(const bf16x8*)(
            wpk + (size_t)((kk * 4 + kg) * 256 + col + nt * 16) * 8);

    // ---- issue chunk-0 loads (chunk == pair; j = lr, clamp 31->30) ----
    const int jc = (lr < 31) ? lr : 30;
    const float* mptr = msg + (size_t)(gp0 * 31 + jc) * 128 + ch2 * 8;
    float4 la = *(const float4*)mptr;
    float4 lb = *(const float4*)(mptr + 4);
    mptr += 31 * 128;

    __syncthreads();

    // ---- phase 1: emb contribution per pair, +b1 at store ----
    {
      f32x4 aE0 = {0, 0, 0, 0}, aE1 = {0, 0, 0, 0};
#pragma unroll
      for (int kk = 0; kk < 4; ++kk) {
        bf16x8 a = *(const bf16x8*)(
            s_emb + cIdx * 128 + ((kk * 4 + kg) ^ cIdx) * 8);
        aE0 = __builtin_amdgcn_mfma_f32_16x16x32_bf16(Bf[kk][0], a, aE0, 0, 0, 0);
        aE1 = __builtin_amdgcn_mfma_f32_16x16x32_bf16(Bf[kk][1], a, aE1, 0, 0, 0);
      }
      if (cIdx < 8) {
        f32x4 b1a = *(const f32x4*)(b1_el + wv * 32 + kg * 4);
        f32x4 b1b = *(const f32x4*)(b1_el + wv * 32 + 16 + kg * 4);
        *(f32x4*)(s_embc + cIdx * 256 + wv * 32 + kg * 4) = aE0 + b1a;
        *(f32x4*)(s_embc + cIdx * 256 + wv * 32 + 16 + kg * 4) = aE1 + b1b;
      }
    }

    // ---- reload Bf with msg-half fragments ----
#pragma unroll
    for (int nt = 0; nt < 2; ++nt)
#pragma unroll
      for (int kk = 0; kk < 4; ++kk)
        Bf[kk][nt] = *(const bf16x8*)(
            wpk + (size_t)(((kk + 4) * 4 + kg) * 256 + col + nt * 16) * 8);

    // ---- write chunk 0 ----
    {
      uint4 pk;
      pk.x = pk2(la.x, la.y); pk.y = pk2(la.z, la.w);
      pk.z = pk2(lb.x, lb.y); pk.w = pk2(lb.z, lb.w);
      *(uint4*)(s_msg + lr * 128 + ((ch2 ^ (lr & 15)) * 8)) = pk;
    }

    __syncthreads();

    // ---- main: 8 chunks x 2 tiles ----
#pragma unroll 1
    for (int c = 0; c < 8; ++c) {
      if (c < 7) {
        la = *(const float4*)mptr;
        lb = *(const float4*)(mptr + 4);
        mptr += 31 * 128;
      }
      const unsigned short* mb = s_msg + (c & 1) * 4096;
      const float* ec = s_embc + c * 256;
#pragma unroll
      for (int tt = 0; tt < 2; ++tt) {
        f32x4 acc0 = *(const f32x4*)(ec + wv * 32 + kg * 4);
        f32x4 acc1 = *(const f32x4*)(ec + wv * 32 + 16 + kg * 4);
        const unsigned short* mp = mb + (tt * 16 + cIdx) * 128;
#pragma unroll
        for (int kk = 0; kk < 4; ++kk) {
          bf16x8 a = *(const bf16x8*)(mp + ((kk * 4 + kg) ^ cIdx) * 8);
          acc0 = __builtin_amdgcn_mfma_f32_16x16x32_bf16(Bf[kk][0], a, acc0, 0, 0, 0);
          acc1 = __builtin_amdgcn_mfma_f32_16x16x32_bf16(Bf[kk][1], a, acc1, 0, 0, 0);
        }
        f32x4 w2a = *(const f32x4*)(s_w2 + wv * 32 + kg * 4);
        f32x4 w2b = *(const f32x4*)(s_w2 + wv * 32 + 16 + kg * 4);
        float p0 = 0.0f, p1 = 0.0f;
#pragma unroll
        for (int reg = 0; reg < 4; ++reg) {
          p0 += silu_f(acc0[reg]) * w2a[reg];
          p1 += silu_f(acc1[reg]) * w2b[reg];
        }
        float v = p0 + p1;
        v += __shfl_xor(v, 16);
        v += __shfl_xor(v, 32);
        if (kg == 0) s_fp[wv][(c * 2 + tt) * 16 + cIdx] = v;
      }
      if (c < 7) {
        uint4 pk;
        pk.x = pk2(la.x, la.y); pk.y = pk2(la.z, la.w);
        pk.z = pk2(lb.x, lb.y); pk.w = pk2(lb.z, lb.w);
        *(uint4*)(s_msg + ((c + 1) & 1) * 4096 + lr * 128 +
                  ((ch2 ^ (lr & 15)) * 8)) = pk;
      }
      __syncthreads();
    }

    // ---- geometry epilogue ----
    if (tid < 248) {
      int p = tid / 31, jj = tid - p * 31;
      int gp = gp0 + p, b = gp >> 5, i = gp & 31;
      int jidx = jj + (jj >= i ? 1 : 0);
      const float* rsb = rs + b * 96;
      float dx = rsb[jidx * 3 + 0] - rsb[i * 3 + 0];
      float dy = rsb[jidx * 3 + 1] - rsb[i * 3 + 1];
      float dz = rsb[jidx * 3 + 2] - rsb[i * 3 + 2];
      float tq = dx * dx + dy * dy + dz * dz;
      int row = p * 32 + jj;
      float f = b2_el[0];
#pragma unroll
      for (int w = 0; w < 8; ++w) f += s_fp[w][row];
      float g = f * __builtin_amdgcn_rcpf(1.0f + tq * sqrtf(tq));
      atomicAdd(&s_ps[p][0], g * dx);
      atomicAdd(&s_ps[p][1], g * dy);
      atomicAdd(&s_ps[p][2], g * dz);
    }
    if (tid < 8) {
      int gp = gp0 + tid, b = gp >> 5, i = gp & 31;
      float x = rs[(b * 32 + i) * 3 + 0];
      float y = rs[(b * 32 + i) * 3 + 1];
      float z = rs[(b * 32 + i) * 3 + 2];
      float dcy = 1.0f;
#pragma unroll
      for (int n = 0; n < 8; ++n) {
        float dx = x - coords[n * 3 + 0];
        float dy = y - coords[n * 3 + 1];
        float dz = z - coords[n * 3 + 2];
        float tq = dx * dx + dy * dy + dz * dz;
        float zc = chg[n];
        dcy *= tanhf(4.0f * tq * zc * zc);
      }
      s_decay[tid] = dcy;
    }
    __syncthreads();
    if (tid < 24) {
      int p = tid / 3, c = tid - p * 3;
      int gp = gp0 + p;
      atomicAdd(&out[gp * 3 + c], OUT_SCALE * s_decay[p] * s_ps[p][c]);
    }
  } else {
    // ======================= NUC PATH =======================
    const int nbid = bid - EL_BLOCKS;
    const int gp0 = nbid * 8;
    const float* msg = msg_nuc;
    const unsigned short* wp = wpk + 8192 * 8;

    if (tid < 32) ((float*)s_ps)[tid] = 0.0f;

    {
      int p = tid >> 4, ch = tid & 15;
      if (tid < 128) {
        const float* src = emb + (gp0 + p) * 128 + ch * 8;
        float4 v0 = *(const float4*)src;
        float4 v1 = *(const float4*)(src + 4);
        uint4 pk;
        pk.x = pk2(v0.x, v0.y); pk.y = pk2(v0.z, v0.w);
        pk.z = pk2(v1.x, v1.y); pk.w = pk2(v1.z, v1.w);
        *(uint4*)(s_emb + p * 128 + (ch ^ p) * 8) = pk;
      } else if (tid < 256) {
        uint4 z = {0u, 0u, 0u, 0u};
        *(uint4*)(s_emb + p * 128 + (ch ^ (p & 15)) * 8) = z;
      }
      if (tid < 256) s_w2[tid] = w2_nuc[tid];
    }

    bf16x8 Bf[4][2];
    const int col = wv * 32 + cIdx;
#pragma unroll
    for (int nt = 0; nt < 2; ++nt)
#pragma unroll
      for (int kk = 0; kk < 4; ++kk)
        Bf[kk][nt] = *(const bf16x8*)(
            wp + (size_t)((kk * 4 + kg) * 256 + col + nt * 16) * 8);

    const float* mptr = msg + (size_t)(gp0 * 8 + lr) * 128 + ch2 * 8;
    float4 la = *(const float4*)mptr;
    float4 lb = *(const float4*)(mptr + 4);
    mptr += 32 * 128;

    __syncthreads();

    {
      f32x4 aE0 = {0, 0, 0, 0}, aE1 = {0, 0, 0, 0};
#pragma unroll
      for (int kk = 0; kk < 4; ++kk) {
        bf16x8 a = *(const bf16x8*)(
            s_emb + cIdx * 128 + ((kk * 4 + kg) ^ cIdx) * 8);
        aE0 = __builtin_amdgcn_mfma_f32_16x16x32_bf16(Bf[kk][0], a, aE0, 0, 0, 0);
        aE1 = __builtin_amdgcn_mfma_f32_16x16x32_bf16(Bf[kk][1], a, aE1, 0, 0, 0);
      }
      if (cIdx < 8) {
        f32x4 b1a = *(const f32x4*)(b1_nuc + wv * 32 + kg * 4);
        f32x4 b1b = *(const f32x4*)(b1_nuc + wv * 32 + 16 + kg * 4);
        *(f32x4*)(s_embc + cIdx * 256 + wv * 32 + kg * 4) = aE0 + b1a;
        *(f32x4*)(s_embc + cIdx * 256 + wv * 32 + 16 + kg * 4) = aE1 + b1b;
      }
    }

#pragma unroll
    for (int nt = 0; nt < 2; ++nt)
#pragma unroll
      for (int kk = 0; kk < 4; ++kk)
        Bf[kk][nt] = *(const bf16x8*)(
            wp + (size_t)(((kk + 4) * 4 + kg) * 256 + col + nt * 16) * 8);

    {
      uint4 pk;
      pk.x = pk2(la.x, la.y); pk.y = pk2(la.z, la.w);
      pk.z = pk2(lb.x, lb.y); pk.w = pk2(lb.z, lb.w);
      *(uint4*)(s_msg + lr * 128 + ((ch2 ^ (lr & 15)) * 8)) = pk;
    }

    __syncthreads();

#pragma unroll 1
    for (int c = 0; c < 2; ++c) {
      if (c < 1) {
        la = *(const float4*)mptr;
        lb = *(const float4*)(mptr + 4);
      }
      const unsigned short* mb = s_msg + (c & 1) * 4096;
#pragma unroll
      for (int tt = 0; tt < 2; ++tt) {
        int p = 4 * c + 2 * tt + (cIdx >> 3);
        const float* ec = s_embc + p * 256;
        f32x4 acc0 = *(const f32x4*)(ec + wv * 32 + kg * 4);
        f32x4 acc1 = *(const f32x4*)(ec + wv * 32 + 16 + kg * 4);
        const unsigned short* mp = mb + (tt * 16 + cIdx) * 128;
#pragma unroll
        for (int kk = 0; kk < 4; ++kk) {
          bf16x8 a = *(const bf16x8*)(mp + ((kk * 4 + kg) ^ cIdx) * 8);
          acc0 = __builtin_amdgcn_mfma_f32_16x16x32_bf16(Bf[kk][0], a, acc0, 0, 0, 0);
          acc1 = __builtin_amdgcn_mfma_f32_16x16x32_bf16(Bf[kk][1], a, acc1, 0, 0, 0);
        }
        f32x4 w2a = *(const f32x4*)(s_w2 + wv * 32 + kg * 4);
        f32x4 w2b = *(const f32x4*)(s_w2 + wv * 32 + 16 + kg * 4);
        float p0 = 0.0f, p1 = 0.0f;
#pragma unroll
        for (int reg = 0; reg < 4; ++reg) {
          p0 += silu_f(acc0[reg]) * w2a[reg];
          p1 += silu_f(acc1[reg]) * w2b[reg];
        }
        float v = p0 + p1;
        v += __shfl_xor(v, 16);
        v += __shfl_xor(v, 32);
        if (kg == 0) s_fp[wv][(c * 2 + tt) * 16 + cIdx] = v;
      }
      if (c < 1) {
        uint4 pk;
        pk.x = pk2(la.x, la.y); pk.y = pk2(la.z, la.w);
        pk.z = pk2(lb.x, lb.y); pk.w = pk2(lb.z, lb.w);
        *(uint4*)(s_msg + 4096 + lr * 128 + ((ch2 ^ (lr & 15)) * 8)) = pk;
      }
      __syncthreads();
    }

    if (tid < 64) {
      int p = tid >> 3, n = tid & 7;
      int gp = gp0 + p, b = gp >> 5, i = gp & 31;
      float dx = rs[(b * 32 + i) * 3 + 0] - coords[n * 3 + 0];
      float dy = rs[(b * 32 + i) * 3 + 1] - coords[n * 3 + 1];
      float dz = rs[(b * 32 + i) * 3 + 2] - coords[n * 3 + 2];
      float tq = dx * dx + dy * dy + dz * dz;
      float f = b2_nuc[0];
#pragma unroll
      for (int w = 0; w < 8; ++w) f += s_fp[w][tid];
      float g = f * __builtin_amdgcn_rcpf(1.0f + tq * sqrtf(tq));
      atomicAdd(&s_ps[p][0], g * dx);
      atomicAdd(&s_ps[p][1], g * dy);
      atomicAdd(&s_ps[p][2], g * dz);
    }
    if (tid < 8) {
      int gp = gp0 + tid, b = gp >> 5, i = gp & 31;
      float x = rs[(b * 32 + i) * 3 + 0];
      float y = rs[(b * 32 + i) * 3 + 1];
      float z = rs[(b * 32 + i) * 3 + 2];
      float dcy = 1.0f;
#pragma unroll
      for (int n = 0; n < 8; ++n) {
        float dx = x - coords[n * 3 + 0];
        float dy = y - coords[n * 3 + 1];
        float dz = z - coords[n * 3 + 2];
        float tq = dx * dx + dy * dy + dz * dz;
        float zc = chg[n];
        dcy *= tanhf(4.0f * tq * zc * zc);
      }
      s_decay[tid] = dcy;
    }
    __syncthreads();
    if (tid < 24) {
      int p = tid / 3, c = tid - p * 3;
      int gp = gp0 + p;
      atomicAdd(&out[gp * 3 + c], OUT_SCALE * s_decay[p] * s_ps[p][c]);
    }
  }
}

extern "C" void kernel_launch(void* const* d_in, const int* in_sizes, int n_in,
                              void* d_out, int out_size, void* d_ws, size_t ws_size,
                              hipStream_t stream) {
  const float* rs       = (const float*)d_in[0];
  const float* coords   = (const float*)d_in[1];
  const float* msg_el   = (const float*)d_in[2];
  const float* msg_nuc  = (const float*)d_in[3];
  const float* emb      = (const float*)d_in[4];
  const float* w1_el    = (const float*)d_in[5];
  const float* b1_el    = (const float*)d_in[6];
  const float* w2_el    = (const float*)d_in[7];
  const float* b2_el    = (const float*)d_in[8];
  const float* w1_nuc   = (const float*)d_in[9];
  const float* b1_nuc   = (const float*)d_in[10];
  const float* w2_nuc   = (const float*)d_in[11];
  const float* b2_nuc   = (const float*)d_in[12];
  const float* chg      = (const float*)d_in[13];
  float* out = (float*)d_out;

  unsigned short* wpk = (unsigned short*)d_ws;  // 256 KB used

  hipMemsetAsync(out, 0, (size_t)out_size * sizeof(float), stream);
  prep_w1<<<64, 256, 0, stream>>>(w1_el, w1_nuc, wpk);
  bf_main_kernel<<<EL_BLOCKS + NUC_BLOCKS, 512, 0, stream>>>(
      rs, msg_el, msg_nuc, emb, wpk, b1_el, w2_el, b2_el, b1_nuc, w2_nuc,
      b2_nuc, coords, chg, out);
}

// Round 10
// 132.019 us; speedup vs baseline: 2.9723x; 1.3733x over previous
//
#include <hip/hip_runtime.h>
#include <hip/hip_bf16.h>

#define OUT_SCALE 0.030197383422318501f  // exp(-3.5)

typedef __attribute__((ext_vector_type(8))) short bf16x8;
typedef __attribute__((ext_vector_type(4))) float f32x4;

#define EL_BLOCKS 2048
#define NUC_BLOCKS 2048

__device__ __forceinline__ unsigned pk2(float a, float b) {
  __hip_bfloat162 h = __float22bfloat162_rn(make_float2(a, b));
  unsigned u;
  __builtin_memcpy(&u, &h, 4);
  return u;
}

__device__ __forceinline__ float silu_f(float h) {
  return h * __builtin_amdgcn_rcpf(1.0f + __expf(-h));
}

// ---------------------------------------------------------------------------
// Prep: pack w1_el / w1_nuc into MFMA fragment layout, bf16.
// Fragment (mlp, kk, kg, col) = 8 bf16 of w1[kk*32+kg*8 .. +8)[col].
// ---------------------------------------------------------------------------
__global__ void prep_w1(const float* __restrict__ w1a,
                        const float* __restrict__ w1b,
                        unsigned short* __restrict__ wp) {
  int gid = blockIdx.x * 256 + threadIdx.x;  // 16384 fragments
  const float* w1 = (gid < 8192) ? w1a : w1b;
  int rem = gid & 8191;
  int kk = rem >> 10;
  int kg = (rem >> 8) & 3;
  int col = rem & 255;
  const float* src = w1 + (kk * 32 + kg * 8) * 256 + col;
  uint4 v;
  v.x = pk2(src[0 * 256], src[1 * 256]);
  v.y = pk2(src[2 * 256], src[3 * 256]);
  v.z = pk2(src[4 * 256], src[5 * 256]);
  v.w = pk2(src[6 * 256], src[7 * 256]);
  *(uint4*)(wp + (size_t)gid * 8) = v;
}

// ---------------------------------------------------------------------------
// Fused main kernel, 512 threads = 8 waves x 32 hidden-cols, 8 pairs/block
// for BOTH paths. el: 256 padded rows = 8 chunks of 32 (chunk == pair).
// nuc: 64 rows = 2 chunks of 32.
// Phase 1: emb contribution (+b1) once per pair -> s_embc[8][256].
// Main: double-buffered 32-row msg chunks, issue-early/write-late, one
// barrier per chunk; per tile only 4 msg MFMAs + acc-init ds_read.
// LDS ~38KB; launch_bounds(512,4): NO SPILL (r7-proven; (512,6) and (512,8)
// both spilled -- r8: 278MB, r9: 115MB scratch writes). At ~60-70 live VGPR
// the HW fits 3 blocks/CU (75%) since LDS no longer caps residency.
// ---------------------------------------------------------------------------
__global__ __launch_bounds__(512, 4) void bf_main_kernel(
    const float* __restrict__ rs, const float* __restrict__ msg_el,
    const float* __restrict__ msg_nuc, const float* __restrict__ emb,
    const unsigned short* __restrict__ wpk,
    const float* __restrict__ b1_el, const float* __restrict__ w2_el,
    const float* __restrict__ b2_el,
    const float* __restrict__ b1_nuc, const float* __restrict__ w2_nuc,
    const float* __restrict__ b2_nuc,
    const float* __restrict__ coords, const float* __restrict__ chg,
    float* __restrict__ out) {
  __shared__ __align__(16) unsigned short s_emb[16 * 128];   // 4 KB
  __shared__ __align__(16) unsigned short s_msg[2 * 32 * 128];  // 16 KB
  __shared__ __align__(16) float s_embc[8 * 256];            // 8 KB
  __shared__ __align__(16) float s_w2[256];                  // 1 KB
  __shared__ float s_fp[8][256];                             // 8 KB
  __shared__ float s_ps[8][4];
  __shared__ float s_decay[8];

  const int tid = threadIdx.x;
  const int bid = blockIdx.x;
  const int lane = tid & 63;
  const int wv = tid >> 6;
  const int cIdx = lane & 15, kg = lane >> 4;
  const int lr = tid >> 4, ch2 = tid & 15;  // staging row / chunk

  if (bid < EL_BLOCKS) {
    // ======================= EL PATH =======================
    const int gp0 = bid * 8;
    const float* msg = msg_el;

    if (tid < 32) ((float*)s_ps)[tid] = 0.0f;

    // ---- stage emb (8 pairs, swizzled; zero rows 8..15) ----
    {
      int p = tid >> 4, ch = tid & 15;
      if (tid < 128) {
        const float* src = emb + (gp0 + p) * 128 + ch * 8;
        float4 v0 = *(const float4*)src;
        float4 v1 = *(const float4*)(src + 4);
        uint4 pk;
        pk.x = pk2(v0.x, v0.y); pk.y = pk2(v0.z, v0.w);
        pk.z = pk2(v1.x, v1.y); pk.w = pk2(v1.z, v1.w);
        *(uint4*)(s_emb + p * 128 + (ch ^ p) * 8) = pk;
      } else if (tid < 256) {
        uint4 z = {0u, 0u, 0u, 0u};
        *(uint4*)(s_emb + p * 128 + (ch ^ (p & 15)) * 8) = z;
      }
      if (tid < 256) s_w2[tid] = w2_el[tid];
    }

    // ---- W1 emb-half fragments ----
    bf16x8 Bf[4][2];
    const int col = wv * 32 + cIdx;
#pragma unroll
    for (int nt = 0; nt < 2; ++nt)
#pragma unroll
      for (int kk = 0; kk < 4; ++kk)
        Bf[kk][nt] = *(const bf16x8*)(
            wpk + (size_t)((kk * 4 + kg) * 256 + col + nt * 16) * 8);

    // ---- issue chunk-0 loads (chunk == pair; j = lr, clamp 31->30) ----
    const int jc = (lr < 31) ? lr : 30;
    const float* mptr = msg + (size_t)(gp0 * 31 + jc) * 128 + ch2 * 8;
    float4 la = *(const float4*)mptr;
    float4 lb = *(const float4*)(mptr + 4);
    mptr += 31 * 128;

    __syncthreads();

    // ---- phase 1: emb contribution per pair, +b1 at store ----
    {
      f32x4 aE0 = {0, 0, 0, 0}, aE1 = {0, 0, 0, 0};
#pragma unroll
      for (int kk = 0; kk < 4; ++kk) {
        bf16x8 a = *(const bf16x8*)(
            s_emb + cIdx * 128 + ((kk * 4 + kg) ^ cIdx) * 8);
        aE0 = __builtin_amdgcn_mfma_f32_16x16x32_bf16(Bf[kk][0], a, aE0, 0, 0, 0);
        aE1 = __builtin_amdgcn_mfma_f32_16x16x32_bf16(Bf[kk][1], a, aE1, 0, 0, 0);
      }
      if (cIdx < 8) {
        f32x4 b1a = *(const f32x4*)(b1_el + wv * 32 + kg * 4);
        f32x4 b1b = *(const f32x4*)(b1_el + wv * 32 + 16 + kg * 4);
        *(f32x4*)(s_embc + cIdx * 256 + wv * 32 + kg * 4) = aE0 + b1a;
        *(f32x4*)(s_embc + cIdx * 256 + wv * 32 + 16 + kg * 4) = aE1 + b1b;
      }
    }

    // ---- reload Bf with msg-half fragments ----
#pragma unroll
    for (int nt = 0; nt < 2; ++nt)
#pragma unroll
      for (int kk = 0; kk < 4; ++kk)
        Bf[kk][nt] = *(const bf16x8*)(
            wpk + (size_t)(((kk + 4) * 4 + kg) * 256 + col + nt * 16) * 8);

    // ---- write chunk 0 ----
    {
      uint4 pk;
      pk.x = pk2(la.x, la.y); pk.y = pk2(la.z, la.w);
      pk.z = pk2(lb.x, lb.y); pk.w = pk2(lb.z, lb.w);
      *(uint4*)(s_msg + lr * 128 + ((ch2 ^ (lr & 15)) * 8)) = pk;
    }

    __syncthreads();

    // ---- main: 8 chunks x 2 tiles ----
#pragma unroll 1
    for (int c = 0; c < 8; ++c) {
      if (c < 7) {
        la = *(const float4*)mptr;
        lb = *(const float4*)(mptr + 4);
        mptr += 31 * 128;
      }
      const unsigned short* mb = s_msg + (c & 1) * 4096;
      const float* ec = s_embc + c * 256;
#pragma unroll
      for (int tt = 0; tt < 2; ++tt) {
        f32x4 acc0 = *(const f32x4*)(ec + wv * 32 + kg * 4);
        f32x4 acc1 = *(const f32x4*)(ec + wv * 32 + 16 + kg * 4);
        const unsigned short* mp = mb + (tt * 16 + cIdx) * 128;
#pragma unroll
        for (int kk = 0; kk < 4; ++kk) {
          bf16x8 a = *(const bf16x8*)(mp + ((kk * 4 + kg) ^ cIdx) * 8);
          acc0 = __builtin_amdgcn_mfma_f32_16x16x32_bf16(Bf[kk][0], a, acc0, 0, 0, 0);
          acc1 = __builtin_amdgcn_mfma_f32_16x16x32_bf16(Bf[kk][1], a, acc1, 0, 0, 0);
        }
        f32x4 w2a = *(const f32x4*)(s_w2 + wv * 32 + kg * 4);
        f32x4 w2b = *(const f32x4*)(s_w2 + wv * 32 + 16 + kg * 4);
        float p0 = 0.0f, p1 = 0.0f;
#pragma unroll
        for (int reg = 0; reg < 4; ++reg) {
          p0 += silu_f(acc0[reg]) * w2a[reg];
          p1 += silu_f(acc1[reg]) * w2b[reg];
        }
        float v = p0 + p1;
        v += __shfl_xor(v, 16);
        v += __shfl_xor(v, 32);
        if (kg == 0) s_fp[wv][(c * 2 + tt) * 16 + cIdx] = v;
      }
      if (c < 7) {
        uint4 pk;
        pk.x = pk2(la.x, la.y); pk.y = pk2(la.z, la.w);
        pk.z = pk2(lb.x, lb.y); pk.w = pk2(lb.z, lb.w);
        *(uint4*)(s_msg + ((c + 1) & 1) * 4096 + lr * 128 +
                  ((ch2 ^ (lr & 15)) * 8)) = pk;
      }
      __syncthreads();
    }

    // ---- geometry epilogue ----
    if (tid < 248) {
      int p = tid / 31, jj = tid - p * 31;
      int gp = gp0 + p, b = gp >> 5, i = gp & 31;
      int jidx = jj + (jj >= i ? 1 : 0);
      const float* rsb = rs + b * 96;
      float dx = rsb[jidx * 3 + 0] - rsb[i * 3 + 0];
      float dy = rsb[jidx * 3 + 1] - rsb[i * 3 + 1];
      float dz = rsb[jidx * 3 + 2] - rsb[i * 3 + 2];
      float tq = dx * dx + dy * dy + dz * dz;
      int row = p * 32 + jj;
      float f = b2_el[0];
#pragma unroll
      for (int w = 0; w < 8; ++w) f += s_fp[w][row];
      float g = f * __builtin_amdgcn_rcpf(1.0f + tq * sqrtf(tq));
      atomicAdd(&s_ps[p][0], g * dx);
      atomicAdd(&s_ps[p][1], g * dy);
      atomicAdd(&s_ps[p][2], g * dz);
    }
    if (tid < 8) {
      int gp = gp0 + tid, b = gp >> 5, i = gp & 31;
      float x = rs[(b * 32 + i) * 3 + 0];
      float y = rs[(b * 32 + i) * 3 + 1];
      float z = rs[(b * 32 + i) * 3 + 2];
      float dcy = 1.0f;
#pragma unroll
      for (int n = 0; n < 8; ++n) {
        float dx = x - coords[n * 3 + 0];
        float dy = y - coords[n * 3 + 1];
        float dz = z - coords[n * 3 + 2];
        float tq = dx * dx + dy * dy + dz * dz;
        float zc = chg[n];
        dcy *= tanhf(4.0f * tq * zc * zc);
      }
      s_decay[tid] = dcy;
    }
    __syncthreads();
    if (tid < 24) {
      int p = tid / 3, c = tid - p * 3;
      int gp = gp0 + p;
      atomicAdd(&out[gp * 3 + c], OUT_SCALE * s_decay[p] * s_ps[p][c]);
    }
  } else {
    // ======================= NUC PATH =======================
    const int nbid = bid - EL_BLOCKS;
    const int gp0 = nbid * 8;
    const float* msg = msg_nuc;
    const unsigned short* wp = wpk + 8192 * 8;

    if (tid < 32) ((float*)s_ps)[tid] = 0.0f;

    {
      int p = tid >> 4, ch = tid & 15;
      if (tid < 128) {
        const float* src = emb + (gp0 + p) * 128 + ch * 8;
        float4 v0 = *(const float4*)src;
        float4 v1 = *(const float4*)(src + 4);
        uint4 pk;
        pk.x = pk2(v0.x, v0.y); pk.y = pk2(v0.z, v0.w);
        pk.z = pk2(v1.x, v1.y); pk.w = pk2(v1.z, v1.w);
        *(uint4*)(s_emb + p * 128 + (ch ^ p) * 8) = pk;
      } else if (tid < 256) {
        uint4 z = {0u, 0u, 0u, 0u};
        *(uint4*)(s_emb + p * 128 + (ch ^ (p & 15)) * 8) = z;
      }
      if (tid < 256) s_w2[tid] = w2_nuc[tid];
    }

    bf16x8 Bf[4][2];
    const int col = wv * 32 + cIdx;
#pragma unroll
    for (int nt = 0; nt < 2; ++nt)
#pragma unroll
      for (int kk = 0; kk < 4; ++kk)
        Bf[kk][nt] = *(const bf16x8*)(
            wp + (size_t)((kk * 4 + kg) * 256 + col + nt * 16) * 8);

    const float* mptr = msg + (size_t)(gp0 * 8 + lr) * 128 + ch2 * 8;
    float4 la = *(const float4*)mptr;
    float4 lb = *(const float4*)(mptr + 4);
    mptr += 32 * 128;

    __syncthreads();

    {
      f32x4 aE0 = {0, 0, 0, 0}, aE1 = {0, 0, 0, 0};
#pragma unroll
      for (int kk = 0; kk < 4; ++kk) {
        bf16x8 a = *(const bf16x8*)(
            s_emb + cIdx * 128 + ((kk * 4 + kg) ^ cIdx) * 8);
        aE0 = __builtin_amdgcn_mfma_f32_16x16x32_bf16(Bf[kk][0], a, aE0, 0, 0, 0);
        aE1 = __builtin_amdgcn_mfma_f32_16x16x32_bf16(Bf[kk][1], a, aE1, 0, 0, 0);
      }
      if (cIdx < 8) {
        f32x4 b1a = *(const f32x4*)(b1_nuc + wv * 32 + kg * 4);
        f32x4 b1b = *(const f32x4*)(b1_nuc + wv * 32 + 16 + kg * 4);
        *(f32x4*)(s_embc + cIdx * 256 + wv * 32 + kg * 4) = aE0 + b1a;
        *(f32x4*)(s_embc + cIdx * 256 + wv * 32 + 16 + kg * 4) = aE1 + b1b;
      }
    }

#pragma unroll
    for (int nt = 0; nt < 2; ++nt)
#pragma unroll
      for (int kk = 0; kk < 4; ++kk)
        Bf[kk][nt] = *(const bf16x8*)(
            wp + (size_t)(((kk + 4) * 4 + kg) * 256 + col + nt * 16) * 8);

    {
      uint4 pk;
      pk.x = pk2(la.x, la.y); pk.y = pk2(la.z, la.w);
      pk.z = pk2(lb.x, lb.y); pk.w = pk2(lb.z, lb.w);
      *(uint4*)(s_msg + lr * 128 + ((ch2 ^ (lr & 15)) * 8)) = pk;
    }

    __syncthreads();

#pragma unroll 1
    for (int c = 0; c < 2; ++c) {
      if (c < 1) {
        la = *(const float4*)mptr;
        lb = *(const float4*)(mptr + 4);
      }
      const unsigned short* mb = s_msg + (c & 1) * 4096;
#pragma unroll
      for (int tt = 0; tt < 2; ++tt) {
        int p = 4 * c + 2 * tt + (cIdx >> 3);
        const float* ec = s_embc + p * 256;
        f32x4 acc0 = *(const f32x4*)(ec + wv * 32 + kg * 4);
        f32x4 acc1 = *(const f32x4*)(ec + wv * 32 + 16 + kg * 4);
        const unsigned short* mp = mb + (tt * 16 + cIdx) * 128;
#pragma unroll
        for (int kk = 0; kk < 4; ++kk) {
          bf16x8 a = *(const bf16x8*)(mp + ((kk * 4 + kg) ^ cIdx) * 8);
          acc0 = __builtin_amdgcn_mfma_f32_16x16x32_bf16(Bf[kk][0], a, acc0, 0, 0, 0);
          acc1 = __builtin_amdgcn_mfma_f32_16x16x32_bf16(Bf[kk][1], a, acc1, 0, 0, 0);
        }
        f32x4 w2a = *(const f32x4*)(s_w2 + wv * 32 + kg * 4);
        f32x4 w2b = *(const f32x4*)(s_w2 + wv * 32 + 16 + kg * 4);
        float p0 = 0.0f, p1 = 0.0f;
#pragma unroll
        for (int reg = 0; reg < 4; ++reg) {
          p0 += silu_f(acc0[reg]) * w2a[reg];
          p1 += silu_f(acc1[reg]) * w2b[reg];
        }
        float v = p0 + p1;
        v += __shfl_xor(v, 16);
        v += __shfl_xor(v, 32);
        if (kg == 0) s_fp[wv][(c * 2 + tt) * 16 + cIdx] = v;
      }
      if (c < 1) {
        uint4 pk;
        pk.x = pk2(la.x, la.y); pk.y = pk2(la.z, la.w);
        pk.z = pk2(lb.x, lb.y); pk.w = pk2(lb.z, lb.w);
        *(uint4*)(s_msg + 4096 + lr * 128 + ((ch2 ^ (lr & 15)) * 8)) = pk;
      }
      __syncthreads();
    }

    if (tid < 64) {
      int p = tid >> 3, n = tid & 7;
      int gp = gp0 + p, b = gp >> 5, i = gp & 31;
      float dx = rs[(b * 32 + i) * 3 + 0] - coords[n * 3 + 0];
      float dy = rs[(b * 32 + i) * 3 + 1] - coords[n * 3 + 1];
      float dz = rs[(b * 32 + i) * 3 + 2] - coords[n * 3 + 2];
      float tq = dx * dx + dy * dy + dz * dz;
      float f = b2_nuc[0];
#pragma unroll
      for (int w = 0; w < 8; ++w) f += s_fp[w][tid];
      float g = f * __builtin_amdgcn_rcpf(1.0f + tq * sqrtf(tq));
      atomicAdd(&s_ps[p][0], g * dx);
      atomicAdd(&s_ps[p][1], g * dy);
      atomicAdd(&s_ps[p][2], g * dz);
    }
    if (tid < 8) {
      int gp = gp0 + tid, b = gp >> 5, i = gp & 31;
      float x = rs[(b * 32 + i) * 3 + 0];
      float y = rs[(b * 32 + i) * 3 + 1];
      float z = rs[(b * 32 + i) * 3 + 2];
      float dcy = 1.0f;
#pragma unroll
      for (int n = 0; n < 8; ++n) {
        float dx = x - coords[n * 3 + 0];
        float dy = y - coords[n * 3 + 1];
        float dz = z - coords[n * 3 + 2];
        float tq = dx * dx + dy * dy + dz * dz;
        float zc = chg[n];
        dcy *= tanhf(4.0f * tq * zc * zc);
      }
      s_decay[tid] = dcy;
    }
    __syncthreads();
    if (tid < 24) {
      int p = tid / 3, c = tid - p * 3;
      int gp = gp0 + p;
      atomicAdd(&out[gp * 3 + c], OUT_SCALE * s_decay[p] * s_ps[p][c]);
    }
  }
}

extern "C" void kernel_launch(void* const* d_in, const int* in_sizes, int n_in,
                              void* d_out, int out_size, void* d_ws, size_t ws_size,
                              hipStream_t stream) {
  const float* rs       = (const float*)d_in[0];
  const float* coords   = (const float*)d_in[1];
  const float* msg_el   = (const float*)d_in[2];
  const float* msg_nuc  = (const float*)d_in[3];
  const float* emb      = (const float*)d_in[4];
  const float* w1_el    = (const float*)d_in[5];
  const float* b1_el    = (const float*)d_in[6];
  const float* w2_el    = (const float*)d_in[7];
  const float* b2_el    = (const float*)d_in[8];
  const float* w1_nuc   = (const float*)d_in[9];
  const float* b1_nuc   = (const float*)d_in[10];
  const float* w2_nuc   = (const float*)d_in[11];
  const float* b2_nuc   = (const float*)d_in[12];
  const float* chg      = (const float*)d_in[13];
  float* out = (float*)d_out;

  unsigned short* wpk = (unsigned short*)d_ws;  // 256 KB used

  hipMemsetAsync(out, 0, (size_t)out_size * sizeof(float), stream);
  prep_w1<<<64, 256, 0, stream>>>(w1_el, w1_nuc, wpk);
  bf_main_kernel<<<EL_BLOCKS + NUC_BLOCKS, 512, 0, stream>>>(
      rs, msg_el, msg_nuc, emb, wpk, b1_el, w2_el, b2_el, b1_nuc, w2_nuc,
      b2_nuc, coords, chg, out);
}